// Round 15
// baseline (411.934 us; speedup 1.0000x reference)
//
#include <hip/hip_runtime.h>
#include <math.h>

#define N_TOK 2000
#define NH 8
#define HD 32
#define SCALE 25.0f
#define SIM_TH 0.75f
#define EPSF 1e-8f
#define NSLOT 8   // ceil(2000/256)
#define NTAIL 208 // valid lanes in slot 7: 2000 - 7*256
#define SPAD 2048 // padded s_attn stride

typedef _Float16 half2_t __attribute__((ext_vector_type(2)));

__device__ __forceinline__ unsigned rflu(unsigned u) {
  return (unsigned)__builtin_amdgcn_readfirstlane((int)u);
}
__device__ __forceinline__ half2_t u2h(unsigned u) {
  return __builtin_bit_cast(half2_t, u);
}

// f32 += f16x2 . f16x2 (v_dot2_f32_f16; products exact, fp32 accumulate)
__device__ __forceinline__ float fdot2f(unsigned a, unsigned b, float c) {
#if __has_builtin(__builtin_amdgcn_fdot2)
  return __builtin_amdgcn_fdot2(u2h(a), u2h(b), c, false);
#else
  const half2_t ha = u2h(a), hb = u2h(b);
  return c + (float)ha.x * (float)hb.x + (float)ha.y * (float)hb.y;
#endif
}

// packed 4-value block reductions (2 syncs each)
__device__ __forceinline__ void block_sum4(float* v, float* red16) {
#pragma unroll
  for (int off = 32; off > 0; off >>= 1) {
#pragma unroll
    for (int q = 0; q < 4; q++) v[q] += __shfl_xor(v[q], off, 64);
  }
  __syncthreads();
  const int wid = threadIdx.x >> 6;
  if ((threadIdx.x & 63) == 0) {
#pragma unroll
    for (int q = 0; q < 4; q++) red16[wid * 4 + q] = v[q];
  }
  __syncthreads();
#pragma unroll
  for (int q = 0; q < 4; q++) {
    v[q] = (red16[q] + red16[4 + q]) + (red16[8 + q] + red16[12 + q]);
  }
}
__device__ __forceinline__ void block_max4(float* v, float* red16) {
#pragma unroll
  for (int off = 32; off > 0; off >>= 1) {
#pragma unroll
    for (int q = 0; q < 4; q++) v[q] = fmaxf(v[q], __shfl_xor(v[q], off, 64));
  }
  __syncthreads();
  const int wid = threadIdx.x >> 6;
  if ((threadIdx.x & 63) == 0) {
#pragma unroll
    for (int q = 0; q < 4; q++) red16[wid * 4 + q] = v[q];
  }
  __syncthreads();
#pragma unroll
  for (int q = 0; q < 4; q++) {
    v[q] = fmaxf(fmaxf(red16[q], red16[4 + q]),
                 fmaxf(red16[8 + q], red16[12 + q]));
  }
}

// ---------------------------------------------------------------------------
// Kernel 1: QKV projection + l2norm; 4 rows/block (r13 variant — measured
// faster than 8-row). f16 normalized planes [h][gg=d/8][n][8] + fp32 v_rm.
// grid = (500, 2), block = 256
// ---------------------------------------------------------------------------
__global__ __launch_bounds__(256) void qkv_norm_kernel(
    const float* __restrict__ x_cls, const float* __restrict__ x_reg,
    const float* __restrict__ W_cls, const float* __restrict__ W_reg,
    _Float16* __restrict__ qc_h, _Float16* __restrict__ qr_h,
    _Float16* __restrict__ kc_h, _Float16* __restrict__ kr_h,
    _Float16* __restrict__ vn_h, float* __restrict__ v_rm) {
  __shared__ float xs[4][256];
  __shared__ float res[4][768];
  __shared__ float inv_norm[96];

  const int n0 = blockIdx.x * 4;
  const int which = blockIdx.y;
  const int tid = threadIdx.x;
  const float* __restrict__ x = which ? x_reg : x_cls;
  const float* __restrict__ W = which ? W_reg : W_cls;

#pragma unroll
  for (int r = 0; r < 4; r++) xs[r][tid] = x[(n0 + r) * 256 + tid];
  __syncthreads();

  float acc[4][3];
#pragma unroll
  for (int r = 0; r < 4; r++) acc[r][0] = acc[r][1] = acc[r][2] = 0.f;

  for (int k = 0; k < 256; k++) {
    const float* __restrict__ wr = W + k * 768;
    const float w0 = wr[tid], w1 = wr[tid + 256], w2 = wr[tid + 512];
#pragma unroll
    for (int r = 0; r < 4; r++) {
      const float xv = xs[r][k];
      acc[r][0] += xv * w0;
      acc[r][1] += xv * w1;
      acc[r][2] += xv * w2;
    }
  }
#pragma unroll
  for (int r = 0; r < 4; r++) {
    res[r][tid] = acc[r][0];
    res[r][tid + 256] = acc[r][1];
    res[r][tid + 512] = acc[r][2];
  }
  __syncthreads();

  if (tid < 96) {
    const int r = tid / 24, grp = tid % 24;
    float ss = 0.f;
#pragma unroll
    for (int d = 0; d < HD; d++) {
      const float v = res[r][grp * 32 + d];
      ss += v * v;
    }
    inv_norm[tid] = 1.0f / (sqrtf(ss) + EPSF);
  }
  __syncthreads();

#pragma unroll
  for (int j = 0; j < 3; j++) {
    const int c = tid + j * 256;
    const int qkv = c >> 8, grp = c >> 5;
    const int h = grp & 7, d = c & 31;
    const int gg = d >> 3, dd = d & 7;
#pragma unroll
    for (int r = 0; r < 4; r++) {
      const int n = n0 + r;
      const float val = res[r][c];
      const float nval = val * inv_norm[r * 24 + grp];
      const size_t fi = ((size_t)(h * 4 + gg) * N_TOK + n) * 8 + dd;
      if (qkv == 0) {
        (which ? qr_h : qc_h)[fi] = (_Float16)nval;
      } else if (qkv == 1) {
        (which ? kr_h : kc_h)[fi] = (_Float16)nval;
      } else if (which == 0) {
        v_rm[(h * N_TOK + n) * HD + d] = val;
        vn_h[fi] = (_Float16)nval;
      }
    }
  }
}

// ---------------------------------------------------------------------------
// Kernel 2: TQ=4 (traffic halved vs r13: 5.1 -> 2.56 TB) with LDS kept at
// ~51.7 KB so TWO blocks/CU stay resident (r14's 65 KB left only a 1 KB
// margin to the 128 KB pair limit -> 1 block/CU -> achieved BW halved).
// Change vs r14: er values stored as f16 in LDS (16 KB instead of 32 KB),
// union'd with part4 (stride 9; disjoint lifetimes). Everything else
// identical to r14. grid = 500, block = 256
// ---------------------------------------------------------------------------
__global__ __launch_bounds__(256) void attn15_kernel(
    const _Float16* __restrict__ qc_h, const _Float16* __restrict__ qr_h,
    const _Float16* __restrict__ kc_h, const _Float16* __restrict__ kr_h,
    const _Float16* __restrict__ vn_h, const float* __restrict__ v_rm,
    float* __restrict__ out_x, float* __restrict__ out_sim) {
  __shared__ float s_attn[4][SPAD];  // 32 KB; tails stay 0 for PV
  __shared__ float s_union[4720];    // 18.9 KB: er f16[4][2000] / part4 str-9
  __shared__ float red[16];

  _Float16* __restrict__ s_erh = (_Float16*)s_union;  // [4][2000]
  float4* __restrict__ part4 = (float4*)s_union;      // stride-9, 1178 used

  const int tid = threadIdx.x;
  const int i0 = blockIdx.x * 4;
  int bsq[4];
#pragma unroll
  for (int q = 0; q < 4; q++) bsq[q] = ((i0 + q) / 10) * 10;

  float sim[4][NSLOT], raw[4][NSLOT];
#pragma unroll
  for (int q = 0; q < 4; q++) {
#pragma unroll
    for (int t = 0; t < NSLOT; t++) { sim[q][t] = 0.f; raw[q][t] = 0.f; }
  }
  if (tid < SPAD - N_TOK) {
#pragma unroll
    for (int q = 0; q < 4; q++) s_attn[q][N_TOK + tid] = 0.f;
  }
  __syncthreads();

  unsigned qp[4][16];  // packed f16 query quad, wave-uniform

  // load a query quad's packed-f16 rows into uniform uints
  auto load_qquad = [&](const _Float16* buf, int h) {
    const uint4* __restrict__ qb = (const uint4*)buf + (size_t)h * 4 * N_TOK;
#pragma unroll
    for (int q = 0; q < 4; q++) {
#pragma unroll
      for (int gg = 0; gg < 4; gg++) {
        const uint4 a = qb[gg * N_TOK + (i0 + q)];
        qp[q][4 * gg + 0] = rflu(a.x);
        qp[q][4 * gg + 1] = rflu(a.y);
        qp[q][4 * gg + 2] = rflu(a.z);
        qp[q][4 * gg + 3] = rflu(a.w);
      }
    }
  };

  // pipelined sweep: 4+4 double-buffered kv; 64 fdot2 per batch; emit(t,d[4])
  auto sweep = [&](const uint4* __restrict__ kt4, auto&& emit) {
    uint4 ka[4], kb[4];
#pragma unroll
    for (int g_ = 0; g_ < 4; g_++) ka[g_] = kt4[g_ * N_TOK + tid];  // t=0
#pragma unroll
    for (int t = 0; t < NSLOT; t++) {
      if (t < NSLOT - 1) {
        const int m1 = tid + 256 * (t + 1);
        const bool v1 = (t + 1 < 7) || (tid < NTAIL);
        const int mc1 = v1 ? m1 : (N_TOK - 1);
#pragma unroll
        for (int g_ = 0; g_ < 4; g_++) kb[g_] = kt4[g_ * N_TOK + mc1];
      }
      float d[4] = {0.f, 0.f, 0.f, 0.f};
#pragma unroll
      for (int g_ = 0; g_ < 4; g_++) {
#pragma unroll
        for (int q = 0; q < 4; q++) {
          d[q] = fdot2f(ka[g_].x, qp[q][4 * g_ + 0], d[q]);
          d[q] = fdot2f(ka[g_].y, qp[q][4 * g_ + 1], d[q]);
          d[q] = fdot2f(ka[g_].z, qp[q][4 * g_ + 2], d[q]);
          d[q] = fdot2f(ka[g_].w, qp[q][4 * g_ + 3], d[q]);
        }
      }
      emit(t, d);
#pragma unroll
      for (int g_ = 0; g_ < 4; g_++) ka[g_] = kb[g_];
    }
  };

  for (int hh = 0; hh < NH; hh++) {
    const int h = (blockIdx.x + hh) & 7;  // XCD-local head schedule

    // ===== phase C: cls scores -> e = exp(s-25) -> s_attn + running sums ===
    load_qquad(qc_h, h);
    float ls[4] = {0.f, 0.f, 0.f, 0.f};
    sweep((const uint4*)kc_h + (size_t)h * 4 * N_TOK,
          [&](int t, float* d) {
            const int m = tid + 256 * t;
            const bool valid = (t < 7) || (tid < NTAIL);
#pragma unroll
            for (int q = 0; q < 4; q++) {
              const float e = valid ? __expf(d[q] * SCALE - SCALE) : 0.f;
              ls[q] += e;
              if (valid) s_attn[q][m] = e;
            }
          });
    block_sum4(ls, red);
    float nc[4];
#pragma unroll
    for (int q = 0; q < 4; q++) nc[q] = 0.5f / ls[q];

    // ===== phase R: reg scores -> s_erh (f16, own slots) + running sums ====
    load_qquad(qr_h, h);
    float lr[4] = {0.f, 0.f, 0.f, 0.f};
    sweep((const uint4*)kr_h + (size_t)h * 4 * N_TOK,
          [&](int t, float* d) {
            const int m = tid + 256 * t;
            const bool valid = (t < 7) || (tid < NTAIL);
#pragma unroll
            for (int q = 0; q < 4; q++) {
              const float e = valid ? __expf(d[q] * SCALE - SCALE) : 0.f;
              lr[q] += e;
              if (valid) s_erh[q * N_TOK + m] = (_Float16)e;
            }
          });
    block_sum4(lr, red);
    float nr[4];
#pragma unroll
    for (int q = 0; q < 4; q++) nr[q] = 0.5f / lr[q];

    // ===== combine, mask, sim += =====
#pragma unroll
    for (int t = 0; t < NSLOT; t++) {
      const int m = tid + 256 * t;
      if ((t < 7) || (tid < NTAIL)) {
#pragma unroll
        for (int q = 0; q < 4; q++) {
          float a = s_attn[q][m] * nc[q] +
                    (float)s_erh[q * N_TOK + m] * nr[q];
          if (m >= bsq[q] && m < bsq[q] + 9 && m != i0 + q) a = 0.f;
          s_attn[q][m] = a;
          sim[q][t] += a;
        }
      }
    }

    // ===== phase V: vn cosine -> raw += =====
    load_qquad(vn_h, h);
    sweep((const uint4*)vn_h + (size_t)h * 4 * N_TOK,
          [&](int t, float* d) {
            const bool valid = (t < 7) || (tid < NTAIL);
            if (valid) {
#pragma unroll
              for (int q = 0; q < 4; q++) raw[q][t] += d[q];
            }
          });
    __syncthreads();  // s_attn final; s_erh reads done -> part4 may reuse

    // ===== attn @ V : fp32 V, 4 queries share each v4 load; rotated m-order
    {
      const int g2 = tid & 7, slice = tid >> 3;
      const int m0 = slice * 64;
      float4 acc[4];
#pragma unroll
      for (int q = 0; q < 4; q++) acc[q] = (float4){0.f, 0.f, 0.f, 0.f};
      const float4* __restrict__ v4 = (const float4*)v_rm + (size_t)h * N_TOK * 8;
#pragma unroll 4
      for (int j = 0; j < 16; j++) {
        const int m = m0 + 4 * ((j + slice) & 15);  // bank-disjoint slices
        float4 av[4];
#pragma unroll
        for (int q = 0; q < 4; q++) av[q] = *(const float4*)&s_attn[q][m];
        // pad rows (m>=2000) have a==0; OOB v4 reads stay inside d_ws (f16
        // plane bytes cannot alias to f32 NaN/Inf).
        const float4 vv0 = v4[(size_t)(m + 0) * 8 + g2];
        const float4 vv1 = v4[(size_t)(m + 1) * 8 + g2];
        const float4 vv2 = v4[(size_t)(m + 2) * 8 + g2];
        const float4 vv3 = v4[(size_t)(m + 3) * 8 + g2];
#pragma unroll
        for (int q = 0; q < 4; q++) {
          acc[q].x += av[q].x * vv0.x; acc[q].y += av[q].x * vv0.y;
          acc[q].z += av[q].x * vv0.z; acc[q].w += av[q].x * vv0.w;
          acc[q].x += av[q].y * vv1.x; acc[q].y += av[q].y * vv1.y;
          acc[q].z += av[q].y * vv1.z; acc[q].w += av[q].y * vv1.w;
          acc[q].x += av[q].z * vv2.x; acc[q].y += av[q].z * vv2.y;
          acc[q].z += av[q].z * vv2.z; acc[q].w += av[q].z * vv2.w;
          acc[q].x += av[q].w * vv3.x; acc[q].y += av[q].w * vv3.y;
          acc[q].z += av[q].w * vv3.z; acc[q].w += av[q].w * vv3.w;
        }
      }
#pragma unroll
      for (int q = 0; q < 4; q++) {
        part4[(slice * 4 + q) * 9 + g2] = acc[q];
      }
    }
    __syncthreads();
    if (tid < 32) {
      const int q = tid >> 3, g = tid & 7;
      float4 s = {0.f, 0.f, 0.f, 0.f};
#pragma unroll 8
      for (int sl = 0; sl < 32; sl++) {
        const float4 p = part4[(sl * 4 + q) * 9 + g];
        s.x += p.x; s.y += p.y; s.z += p.z; s.w += p.w;
      }
      *(float4*)(out_x + (size_t)(i0 + q) * 512 + h * 32 + 4 * g) = s;
    } else if (tid >= 64 && tid < 192) {
      const int idx = tid - 64;
      const int q = idx >> 5, d = idx & 31;
      out_x[(size_t)(i0 + q) * 512 + 256 + h * 32 + d] =
          v_rm[((size_t)h * N_TOK + i0 + q) * HD + d];
    }
    __syncthreads();  // part4 reads done -> s_erh/s_attn reuse next head
  }

  // ===== sim_round2 epilogue, packed 4-query reductions =====
  float lm[4] = {-1e30f, -1e30f, -1e30f, -1e30f};
#pragma unroll
  for (int t = 0; t < NSLOT; t++) {
    if ((t < 7) || (tid < NTAIL)) {
#pragma unroll
      for (int q = 0; q < 4; q++) lm[q] = fmaxf(lm[q], sim[q][t] * 0.125f);
    }
  }
  block_max4(lm, red);

  float ls[4] = {0.f, 0.f, 0.f, 0.f};
#pragma unroll
  for (int t = 0; t < NSLOT; t++) {
    const bool valid = (t < 7) || (tid < NTAIL);
#pragma unroll
    for (int q = 0; q < 4; q++) {
      const float e = valid ? __expf(sim[q][t] * 0.125f - lm[q]) : 0.f;
      sim[q][t] = e;
      ls[q] += e;
    }
  }
  block_sum4(ls, red);
  float invS[4];
#pragma unroll
  for (int q = 0; q < 4; q++) invS[q] = 1.0f / ls[q];

  float lms[4] = {0.f, 0.f, 0.f, 0.f};
#pragma unroll
  for (int t = 0; t < NSLOT; t++) {
    const bool valid = (t < 7) || (tid < NTAIL);
#pragma unroll
    for (int q = 0; q < 4; q++) {
      const float p = sim[q][t] * invS[q];
      const float mp = (valid && (raw[q][t] * 0.125f > SIM_TH)) ? p : 0.f;
      sim[q][t] = mp;
      lms[q] += mp;
    }
  }
  block_sum4(lms, red);
  float invMS[4];
#pragma unroll
  for (int q = 0; q < 4; q++) invMS[q] = 1.0f / (lms[q] + EPSF);

#pragma unroll
  for (int t = 0; t < NSLOT; t++) {
    const int m = tid + 256 * t;
    if ((t < 7) || (tid < NTAIL)) {
#pragma unroll
      for (int q = 0; q < 4; q++) {
        out_sim[(size_t)(i0 + q) * N_TOK + m] = sim[q][t] * invMS[q];
      }
    }
  }
}

// ---------------------------------------------------------------------------
extern "C" void kernel_launch(void* const* d_in, const int* in_sizes, int n_in,
                              void* d_out, int out_size, void* d_ws,
                              size_t ws_size, hipStream_t stream) {
  const float* x_cls = (const float*)d_in[0];
  const float* x_reg = (const float*)d_in[1];
  const float* W_cls = (const float*)d_in[2];
  const float* W_reg = (const float*)d_in[3];

  // ws layout: v_rm fp32 first (PV OOB-clamped reads land in f16 planes,
  // which cannot alias to f32 NaN), then five f16 plane buffers
  const size_t seg = (size_t)NH * N_TOK * HD;  // 512000 elements
  float* v_rm = (float*)d_ws;
  _Float16* qc_h = (_Float16*)(v_rm + seg);
  _Float16* qr_h = qc_h + seg;
  _Float16* kc_h = qr_h + seg;
  _Float16* kr_h = kc_h + seg;
  _Float16* vn_h = kr_h + seg;

  dim3 g1(500, 2);
  qkv_norm_kernel<<<g1, 256, 0, stream>>>(x_cls, x_reg, W_cls, W_reg, qc_h,
                                          qr_h, kc_h, kr_h, vn_h, v_rm);

  float* out_x = (float*)d_out;                  // [2000, 512]
  float* out_sim = out_x + (size_t)N_TOK * 512;  // [2000, 2000]
  attn15_kernel<<<500, 256, 0, stream>>>(qc_h, qr_h, kc_h, kr_h, vn_h, v_rm,
                                         out_x, out_sim);
}

// Round 16
// 308.072 us; speedup vs baseline: 1.3371x; 1.3371x over previous
//
#include <hip/hip_runtime.h>
#include <math.h>

#define N_TOK 2000
#define NH 8
#define HD 32
#define SCALE 25.0f
#define SIM_TH 0.75f
#define EPSF 1e-8f
#define NSLOT 8   // ceil(2000/256)
#define NTAIL 208 // valid lanes in slot 7: 2000 - 7*256
#define SPAD 2048 // padded s_attn stride

typedef _Float16 half2_t __attribute__((ext_vector_type(2)));

__device__ __forceinline__ unsigned rflu(unsigned u) {
  return (unsigned)__builtin_amdgcn_readfirstlane((int)u);
}
__device__ __forceinline__ half2_t u2h(unsigned u) {
  return __builtin_bit_cast(half2_t, u);
}
__device__ __forceinline__ unsigned h2u(half2_t h) {
  return __builtin_bit_cast(unsigned, h);
}

// f32 += f16x2 . f16x2 (v_dot2_f32_f16; products exact, fp32 accumulate)
__device__ __forceinline__ float fdot2f(unsigned a, unsigned b, float c) {
#if __has_builtin(__builtin_amdgcn_fdot2)
  return __builtin_amdgcn_fdot2(u2h(a), u2h(b), c, false);
#else
  const half2_t ha = u2h(a), hb = u2h(b);
  return c + (float)ha.x * (float)hb.x + (float)ha.y * (float)hb.y;
#endif
}

__device__ __forceinline__ float block_max256(float v, float* red) {
#pragma unroll
  for (int off = 32; off > 0; off >>= 1) v = fmaxf(v, __shfl_xor(v, off, 64));
  __syncthreads();
  if ((threadIdx.x & 63) == 0) red[threadIdx.x >> 6] = v;
  __syncthreads();
  return fmaxf(fmaxf(red[0], red[1]), fmaxf(red[2], red[3]));
}
__device__ __forceinline__ float block_sum256(float v, float* red) {
#pragma unroll
  for (int off = 32; off > 0; off >>= 1) v += __shfl_xor(v, off, 64);
  __syncthreads();
  if ((threadIdx.x & 63) == 0) red[threadIdx.x >> 6] = v;
  __syncthreads();
  return (red[0] + red[1]) + (red[2] + red[3]);
}

// load a query pair's packed-f16 row into uniform uints (SGPRs)
#define LOAD_QPAIR(BUF)                                                   \
  {                                                                       \
    const uint4* __restrict__ qb = (const uint4*)(BUF) + (size_t)h * 4 * N_TOK; \
    _Pragma("unroll") for (int gg = 0; gg < 4; gg++) {                    \
      const uint4 a0 = qb[gg * N_TOK + i0];                               \
      const uint4 a1 = qb[gg * N_TOK + i1];                               \
      qp0[4 * gg + 0] = rflu(a0.x); qp0[4 * gg + 1] = rflu(a0.y);         \
      qp0[4 * gg + 2] = rflu(a0.z); qp0[4 * gg + 3] = rflu(a0.w);         \
      qp1[4 * gg + 0] = rflu(a1.x); qp1[4 * gg + 1] = rflu(a1.y);         \
      qp1[4 * gg + 2] = rflu(a1.z); qp1[4 * gg + 3] = rflu(a1.w);         \
    }                                                                     \
  }

// ---------------------------------------------------------------------------
// Kernel 0: pack W fp32 [256][768] into f16 pair-quads Wq[k/8][768] (uint4:
// components pack k-pairs (0,1)(2,3)(4,5)(6,7)). grid = (96, 2), block = 256
// ---------------------------------------------------------------------------
__global__ __launch_bounds__(256) void wpack_kernel(
    const float* __restrict__ W_cls, const float* __restrict__ W_reg,
    unsigned* __restrict__ Wp_cls, unsigned* __restrict__ Wp_reg) {
  const int idx = blockIdx.x * 256 + threadIdx.x;  // uint4 index, 0..24575
  const int kq = idx / 768, c = idx % 768;
  const float* __restrict__ W = blockIdx.y ? W_reg : W_cls;
  uint4* __restrict__ Wq = (uint4*)(blockIdx.y ? Wp_reg : Wp_cls);
  uint4 o;
  o.x = h2u((half2_t){(_Float16)W[(8 * kq + 0) * 768 + c],
                      (_Float16)W[(8 * kq + 1) * 768 + c]});
  o.y = h2u((half2_t){(_Float16)W[(8 * kq + 2) * 768 + c],
                      (_Float16)W[(8 * kq + 3) * 768 + c]});
  o.z = h2u((half2_t){(_Float16)W[(8 * kq + 4) * 768 + c],
                      (_Float16)W[(8 * kq + 5) * 768 + c]});
  o.w = h2u((half2_t){(_Float16)W[(8 * kq + 6) * 768 + c],
                      (_Float16)W[(8 * kq + 7) * 768 + c]});
  Wq[idx] = o;
}

// ---------------------------------------------------------------------------
// Kernel 1: QKV projection via f16 W + fdot2 (W traffic and GEMM VALU both
// halved vs fp32), fused l2norm. Outputs f16 planes + fp32 v_rm + f16 v_h
// row-major for the PV loop. grid = (500, 2), block = 256
// ---------------------------------------------------------------------------
__global__ __launch_bounds__(256) void qkv_norm_kernel(
    const float* __restrict__ x_cls, const float* __restrict__ x_reg,
    const unsigned* __restrict__ Wp_cls, const unsigned* __restrict__ Wp_reg,
    _Float16* __restrict__ qc_h, _Float16* __restrict__ qr_h,
    _Float16* __restrict__ kc_h, _Float16* __restrict__ kr_h,
    _Float16* __restrict__ vn_h, float* __restrict__ v_rm,
    _Float16* __restrict__ v_h) {
  __shared__ unsigned xs_p[4][128];  // packed f16 x rows
  __shared__ float res[4][768];
  __shared__ float inv_norm[96];

  const int n0 = blockIdx.x * 4;
  const int which = blockIdx.y;
  const int tid = threadIdx.x;
  const float* __restrict__ x = which ? x_reg : x_cls;
  const uint4* __restrict__ Wq =
      (const uint4*)(which ? Wp_reg : Wp_cls);

  if (tid < 128) {
#pragma unroll
    for (int r = 0; r < 4; r++) {
      const float2 xv = ((const float2*)x)[(size_t)(n0 + r) * 128 + tid];
      xs_p[r][tid] = h2u((half2_t){(_Float16)xv.x, (_Float16)xv.y});
    }
  }
  __syncthreads();

  float acc[4][3];
#pragma unroll
  for (int r = 0; r < 4; r++) acc[r][0] = acc[r][1] = acc[r][2] = 0.f;

#pragma unroll 2
  for (int kq = 0; kq < 32; kq++) {
    const uint4 w0 = Wq[kq * 768 + tid];
    const uint4 w1 = Wq[kq * 768 + tid + 256];
    const uint4 w2 = Wq[kq * 768 + tid + 512];
#pragma unroll
    for (int r = 0; r < 4; r++) {
      const uint4 xp = *(const uint4*)&xs_p[r][kq * 4];
      acc[r][0] = fdot2f(w0.x, xp.x, acc[r][0]);
      acc[r][0] = fdot2f(w0.y, xp.y, acc[r][0]);
      acc[r][0] = fdot2f(w0.z, xp.z, acc[r][0]);
      acc[r][0] = fdot2f(w0.w, xp.w, acc[r][0]);
      acc[r][1] = fdot2f(w1.x, xp.x, acc[r][1]);
      acc[r][1] = fdot2f(w1.y, xp.y, acc[r][1]);
      acc[r][1] = fdot2f(w1.z, xp.z, acc[r][1]);
      acc[r][1] = fdot2f(w1.w, xp.w, acc[r][1]);
      acc[r][2] = fdot2f(w2.x, xp.x, acc[r][2]);
      acc[r][2] = fdot2f(w2.y, xp.y, acc[r][2]);
      acc[r][2] = fdot2f(w2.z, xp.z, acc[r][2]);
      acc[r][2] = fdot2f(w2.w, xp.w, acc[r][2]);
    }
  }
#pragma unroll
  for (int r = 0; r < 4; r++) {
    res[r][tid] = acc[r][0];
    res[r][tid + 256] = acc[r][1];
    res[r][tid + 512] = acc[r][2];
  }
  __syncthreads();

  if (tid < 96) {
    const int r = tid / 24, grp = tid % 24;
    float ss = 0.f;
#pragma unroll
    for (int d = 0; d < HD; d++) {
      const float v = res[r][grp * 32 + d];
      ss += v * v;
    }
    inv_norm[tid] = 1.0f / (sqrtf(ss) + EPSF);
  }
  __syncthreads();

#pragma unroll
  for (int j = 0; j < 3; j++) {
    const int c = tid + j * 256;
    const int qkv = c >> 8, grp = c >> 5;
    const int h = grp & 7, d = c & 31;
    const int gg = d >> 3, dd = d & 7;
#pragma unroll
    for (int r = 0; r < 4; r++) {
      const int n = n0 + r;
      const float val = res[r][c];
      const float nval = val * inv_norm[r * 24 + grp];
      const size_t fi = ((size_t)(h * 4 + gg) * N_TOK + n) * 8 + dd;
      if (qkv == 0) {
        (which ? qr_h : qc_h)[fi] = (_Float16)nval;
      } else if (qkv == 1) {
        (which ? kr_h : kc_h)[fi] = (_Float16)nval;
      } else if (which == 0) {
        v_rm[(h * N_TOK + n) * HD + d] = val;
        vn_h[fi] = (_Float16)nval;
        v_h[((size_t)h * N_TOK + n) * HD + d] = (_Float16)val;
      }
    }
  }
}

// ---------------------------------------------------------------------------
// Kernel 2: r13 base (TQ=2, fp32 er, pipelined f16 score sweeps) with the PV
// loop reading f16 V row-major: one uint4 = 8 d-components per load (16B
// requests kept; loads & traffic halved vs fp32 V). 64 slices x 4 d-groups;
// rotated m-order keeps av-reads <=2-way. grid = 1000, block = 256
// ---------------------------------------------------------------------------
__global__ __launch_bounds__(256) void attn16_kernel(
    const _Float16* __restrict__ qc_h, const _Float16* __restrict__ qr_h,
    const _Float16* __restrict__ kc_h, const _Float16* __restrict__ kr_h,
    const _Float16* __restrict__ vn_h, const float* __restrict__ v_rm,
    const _Float16* __restrict__ v_h,
    float* __restrict__ out_x, float* __restrict__ out_sim) {
  __shared__ float s_attn[2][SPAD];  // 16 KB; tails stay 0 for PV
  __shared__ float s_union[4608];    // 18.4 KB: er[2][2000] / part (str 17)
  __shared__ float red[4];

  float* __restrict__ s_er = s_union;
  float* __restrict__ part = s_union;  // [64 slices][4 g2] units of 17 floats

  const int tid = threadIdx.x;
  const int i0 = blockIdx.x * 2;
  const int i1 = i0 + 1;
  const int bs = (i0 / 10) * 10;  // i0 even -> i0,i1 share the same decade

  float sim0[NSLOT], sim1[NSLOT], raw0[NSLOT], raw1[NSLOT];
#pragma unroll
  for (int t = 0; t < NSLOT; t++) {
    sim0[t] = 0.f; sim1[t] = 0.f; raw0[t] = 0.f; raw1[t] = 0.f;
  }
  if (tid < SPAD - N_TOK) {
    s_attn[0][N_TOK + tid] = 0.f;
    s_attn[1][N_TOK + tid] = 0.f;
  }
  __syncthreads();

  unsigned qp0[16], qp1[16];  // packed f16 query pairs, wave-uniform -> SGPR

  // pipelined sweep over the 8 m-slots of one f16 K plane: emit(t,d0,d1)
  auto sweep = [&](const uint4* __restrict__ kt4, auto&& emit) {
    uint4 ka[4], kb[4];
#pragma unroll
    for (int g_ = 0; g_ < 4; g_++) ka[g_] = kt4[g_ * N_TOK + tid];  // t=0
#pragma unroll
    for (int t = 0; t < NSLOT; t++) {
      if (t < NSLOT - 1) {  // prefetch t+1 while computing t
        const int m1 = tid + 256 * (t + 1);
        const bool v1 = (t + 1 < 7) || (tid < NTAIL);
        const int mc1 = v1 ? m1 : (N_TOK - 1);
#pragma unroll
        for (int g_ = 0; g_ < 4; g_++) kb[g_] = kt4[g_ * N_TOK + mc1];
      }
      float d0 = 0.f, d1 = 0.f;
#pragma unroll
      for (int g_ = 0; g_ < 4; g_++) {
        d0 = fdot2f(ka[g_].x, qp0[4 * g_ + 0], d0);
        d0 = fdot2f(ka[g_].y, qp0[4 * g_ + 1], d0);
        d0 = fdot2f(ka[g_].z, qp0[4 * g_ + 2], d0);
        d0 = fdot2f(ka[g_].w, qp0[4 * g_ + 3], d0);
        d1 = fdot2f(ka[g_].x, qp1[4 * g_ + 0], d1);
        d1 = fdot2f(ka[g_].y, qp1[4 * g_ + 1], d1);
        d1 = fdot2f(ka[g_].z, qp1[4 * g_ + 2], d1);
        d1 = fdot2f(ka[g_].w, qp1[4 * g_ + 3], d1);
      }
      emit(t, d0, d1);
#pragma unroll
      for (int g_ = 0; g_ < 4; g_++) ka[g_] = kb[g_];
    }
  };

  for (int hh = 0; hh < NH; hh++) {
    const int h = (blockIdx.x + hh) & 7;  // XCD-local head schedule

    // ===== phase C: cls scores -> e = exp(s-25) -> s_attn + running sum ===
    LOAD_QPAIR(qc_h);
    float ls0 = 0.f, ls1 = 0.f;
    sweep((const uint4*)kc_h + (size_t)h * 4 * N_TOK,
          [&](int t, float d0, float d1) {
            const int m = tid + 256 * t;
            const bool valid = (t < 7) || (tid < NTAIL);
            const float e0 = valid ? __expf(d0 * SCALE - SCALE) : 0.f;
            const float e1 = valid ? __expf(d1 * SCALE - SCALE) : 0.f;
            ls0 += e0; ls1 += e1;
            if (valid) {
              s_attn[0][m] = e0;
              s_attn[1][m] = e1;
            }
          });
    const float S0c = block_sum256(ls0, red);
    const float S1c = block_sum256(ls1, red);
    const float n0c = 0.5f / S0c, n1c = 0.5f / S1c;

    // ===== phase R: reg scores -> s_er (own slots only) =====
    LOAD_QPAIR(qr_h);
    float lr0 = 0.f, lr1 = 0.f;
    sweep((const uint4*)kr_h + (size_t)h * 4 * N_TOK,
          [&](int t, float d0, float d1) {
            const int m = tid + 256 * t;
            const bool valid = (t < 7) || (tid < NTAIL);
            const float e0 = valid ? __expf(d0 * SCALE - SCALE) : 0.f;
            const float e1 = valid ? __expf(d1 * SCALE - SCALE) : 0.f;
            lr0 += e0; lr1 += e1;
            if (valid) {
              s_er[m] = e0;
              s_er[N_TOK + m] = e1;
            }
          });
    const float S0r = block_sum256(lr0, red);
    const float S1r = block_sum256(lr1, red);
    const float n0r = 0.5f / S0r, n1r = 0.5f / S1r;

    // ===== combine, mask, sim += =====
#pragma unroll
    for (int t = 0; t < NSLOT; t++) {
      const int m = tid + 256 * t;
      if ((t < 7) || (tid < NTAIL)) {
        float a0 = s_attn[0][m] * n0c + s_er[m] * n0r;
        float a1 = s_attn[1][m] * n1c + s_er[N_TOK + m] * n1r;
        if (m >= bs && m < bs + 9) {
          if (m != i0) a0 = 0.f;
          if (m != i1) a1 = 0.f;
        }
        s_attn[0][m] = a0;
        s_attn[1][m] = a1;
        sim0[t] += a0;
        sim1[t] += a1;
      }
    }

    // ===== phase V: vn cosine -> raw += =====
    LOAD_QPAIR(vn_h);
    sweep((const uint4*)vn_h + (size_t)h * 4 * N_TOK,
          [&](int t, float d0, float d1) {
            const bool valid = (t < 7) || (tid < NTAIL);
            if (valid) { raw0[t] += d0; raw1[t] += d1; }
          });
    __syncthreads();  // s_attn final; s_er reads done -> part may reuse

    // ===== attn @ V : f16 V row-major, one uint4 = 8 d per load =====
    {
      const int g2 = tid & 3;        // d-group of 8
      const int slice = tid >> 2;    // 64 slices x 32 m
      const int m0 = slice * 32;
      float acc0[8], acc1[8];
#pragma unroll
      for (int e = 0; e < 8; e++) { acc0[e] = 0.f; acc1[e] = 0.f; }
      const _Float16* __restrict__ vb =
          v_h + (size_t)h * N_TOK * HD + g2 * 8;
#pragma unroll 2
      for (int jj = 0; jj < 8; jj++) {
        const int m = m0 + 4 * ((jj + slice) & 7);  // rotated: <=2-way LDS
        const float4 av0 = *(const float4*)&s_attn[0][m];
        const float4 av1 = *(const float4*)&s_attn[1][m];
        // m can reach 2047; av=0 there. v_h overrun (<=1.5k elems) lands in
        // the adjacent f16 plane (finite values; x0 = 0). Layout guarantees
        // v_h is not the last ws buffer.
        uint4 vv[4];
#pragma unroll
        for (int mm = 0; mm < 4; mm++) {
          vv[mm] = *(const uint4*)(vb + (size_t)(m + mm) * HD);
        }
#pragma unroll
        for (int mm = 0; mm < 4; mm++) {
          const float a0 = ((const float*)&av0)[mm];
          const float a1 = ((const float*)&av1)[mm];
          const unsigned* vp = (const unsigned*)&vv[mm];
#pragma unroll
          for (int e = 0; e < 4; e++) {
            const half2_t hv = u2h(vp[e]);
            const float vx = (float)hv.x, vy = (float)hv.y;
            acc0[2 * e] += a0 * vx;
            acc0[2 * e + 1] += a0 * vy;
            acc1[2 * e] += a1 * vx;
            acc1[2 * e + 1] += a1 * vy;
          }
        }
      }
      __syncthreads();  // er reads in combine long done; part write safe
      float* pu = part + (size_t)(slice * 4 + g2) * 17;  // stride 17: no bank clash
#pragma unroll
      for (int e = 0; e < 8; e++) {
        pu[e] = acc0[e];
        pu[8 + e] = acc1[e];
      }
    }
    __syncthreads();
    if (tid < 64) {
      const int q = tid >> 5, d = tid & 31;
      const int g = d >> 3, e = d & 7;
      float s = 0.f;
#pragma unroll 8
      for (int sl = 0; sl < 64; sl++) {
        s += part[(size_t)(sl * 4 + g) * 17 + q * 8 + e];
      }
      const int irow = q ? i1 : i0;
      out_x[(size_t)irow * 512 + h * 32 + d] = s;
    } else if (tid >= 64 && tid < 128) {
      const int q = (tid - 64) >> 5, d = (tid - 64) & 31;
      const int irow = q ? i1 : i0;
      out_x[(size_t)irow * 512 + 256 + h * 32 + d] =
          v_rm[((size_t)h * N_TOK + irow) * HD + d];
    }
    __syncthreads();  // part reads done -> s_er reuse next head
  }

  // ===== sim_round2 epilogue, from registers =====
#pragma unroll
  for (int q = 0; q < 2; q++) {
    const int irow = q ? i1 : i0;
    float* __restrict__ sim = q ? sim1 : sim0;
    float* __restrict__ raw = q ? raw1 : raw0;

    float lm = -1e30f;
#pragma unroll
    for (int t = 0; t < NSLOT; t++) {
      if ((t < 7) || (tid < NTAIL)) lm = fmaxf(lm, sim[t] * 0.125f);
    }
    const float M = block_max256(lm, red);

    float ls = 0.f;
#pragma unroll
    for (int t = 0; t < NSLOT; t++) {
      const bool valid = (t < 7) || (tid < NTAIL);
      const float e = valid ? __expf(sim[t] * 0.125f - M) : 0.f;
      sim[t] = e;
      ls += e;
    }
    const float S = block_sum256(ls, red);
    const float invS = 1.0f / S;

    float lms = 0.f;
#pragma unroll
    for (int t = 0; t < NSLOT; t++) {
      const bool valid = (t < 7) || (tid < NTAIL);
      const float p = sim[t] * invS;
      const float mp = (valid && (raw[t] * 0.125f > SIM_TH)) ? p : 0.f;
      sim[t] = mp;
      lms += mp;
    }
    const float MS = block_sum256(lms, red);
    const float invMS = 1.0f / (MS + EPSF);

#pragma unroll
    for (int t = 0; t < NSLOT; t++) {
      const int m = tid + 256 * t;
      if ((t < 7) || (tid < NTAIL)) {
        out_sim[(size_t)irow * N_TOK + m] = sim[t] * invMS;
      }
    }
  }
}

// ---------------------------------------------------------------------------
extern "C" void kernel_launch(void* const* d_in, const int* in_sizes, int n_in,
                              void* d_out, int out_size, void* d_ws,
                              size_t ws_size, hipStream_t stream) {
  const float* x_cls = (const float*)d_in[0];
  const float* x_reg = (const float*)d_in[1];
  const float* W_cls = (const float*)d_in[2];
  const float* W_reg = (const float*)d_in[3];

  // ws layout: v_rm fp32, v_h f16 (NOT last: PV overrun must hit finite f16
  // data), then the score planes, then packed W.
  const size_t seg = (size_t)NH * N_TOK * HD;  // 512000 elements
  float* v_rm = (float*)d_ws;
  _Float16* v_h = (_Float16*)(v_rm + seg);
  _Float16* qc_h = v_h + seg;
  _Float16* qr_h = qc_h + seg;
  _Float16* kc_h = qr_h + seg;
  _Float16* kr_h = kc_h + seg;
  _Float16* vn_h = kr_h + seg;
  unsigned* Wp_cls = (unsigned*)(vn_h + seg);  // 98304 uints each
  unsigned* Wp_reg = Wp_cls + 98304;

  dim3 g0(96, 2);
  wpack_kernel<<<g0, 256, 0, stream>>>(W_cls, W_reg, Wp_cls, Wp_reg);

  dim3 g1(500, 2);
  qkv_norm_kernel<<<g1, 256, 0, stream>>>(x_cls, x_reg, Wp_cls, Wp_reg, qc_h,
                                          qr_h, kc_h, kr_h, vn_h, v_rm, v_h);

  float* out_x = (float*)d_out;                  // [2000, 512]
  float* out_sim = out_x + (size_t)N_TOK * 512;  // [2000, 2000]
  attn16_kernel<<<1000, 256, 0, stream>>>(qc_h, qr_h, kc_h, kr_h, vn_h, v_rm,
                                          v_h, out_x, out_sim);
}

// Round 17
// 301.383 us; speedup vs baseline: 1.3668x; 1.0222x over previous
//
#include <hip/hip_runtime.h>
#include <math.h>

#define N_TOK 2000
#define NH 8
#define HD 32
#define SCALE 25.0f
#define SIM_TH 0.75f
#define EPSF 1e-8f
#define NSLOT 8   // ceil(2000/256)
#define NTAIL 208 // valid lanes in slot 7: 2000 - 7*256
#define SPAD 2048 // padded s_attn stride

typedef _Float16 half2_t __attribute__((ext_vector_type(2)));

__device__ __forceinline__ unsigned rflu(unsigned u) {
  return (unsigned)__builtin_amdgcn_readfirstlane((int)u);
}
__device__ __forceinline__ half2_t u2h(unsigned u) {
  return __builtin_bit_cast(half2_t, u);
}
__device__ __forceinline__ unsigned h2u(half2_t h) {
  return __builtin_bit_cast(unsigned, h);
}

// f32 += f16x2 . f16x2 (v_dot2_f32_f16; products exact, fp32 accumulate)
__device__ __forceinline__ float fdot2f(unsigned a, unsigned b, float c) {
#if __has_builtin(__builtin_amdgcn_fdot2)
  return __builtin_amdgcn_fdot2(u2h(a), u2h(b), c, false);
#else
  const half2_t ha = u2h(a), hb = u2h(b);
  return c + (float)ha.x * (float)hb.x + (float)ha.y * (float)hb.y;
#endif
}

__device__ __forceinline__ float block_max256(float v, float* red) {
#pragma unroll
  for (int off = 32; off > 0; off >>= 1) v = fmaxf(v, __shfl_xor(v, off, 64));
  __syncthreads();
  if ((threadIdx.x & 63) == 0) red[threadIdx.x >> 6] = v;
  __syncthreads();
  return fmaxf(fmaxf(red[0], red[1]), fmaxf(red[2], red[3]));
}
__device__ __forceinline__ float block_sum256(float v, float* red) {
#pragma unroll
  for (int off = 32; off > 0; off >>= 1) v += __shfl_xor(v, off, 64);
  __syncthreads();
  if ((threadIdx.x & 63) == 0) red[threadIdx.x >> 6] = v;
  __syncthreads();
  return (red[0] + red[1]) + (red[2] + red[3]);
}
// one packed block reduction for 4 sums (2 syncs total instead of 8)
__device__ __forceinline__ void block_sum4(float* v, float* red16) {
#pragma unroll
  for (int off = 32; off > 0; off >>= 1) {
#pragma unroll
    for (int q = 0; q < 4; q++) v[q] += __shfl_xor(v[q], off, 64);
  }
  __syncthreads();
  const int wid = threadIdx.x >> 6;
  if ((threadIdx.x & 63) == 0) {
#pragma unroll
    for (int q = 0; q < 4; q++) red16[wid * 4 + q] = v[q];
  }
  __syncthreads();
#pragma unroll
  for (int q = 0; q < 4; q++) {
    v[q] = (red16[q] + red16[4 + q]) + (red16[8 + q] + red16[12 + q]);
  }
}

// load a query pair's packed-f16 row into uniform uints (SGPRs)
#define LOAD_QPAIR(BUF)                                                   \
  {                                                                       \
    const uint4* __restrict__ qb = (const uint4*)(BUF) + (size_t)h * 4 * N_TOK; \
    _Pragma("unroll") for (int gg = 0; gg < 4; gg++) {                    \
      const uint4 a0 = qb[gg * N_TOK + i0];                               \
      const uint4 a1 = qb[gg * N_TOK + i1];                               \
      qp0[4 * gg + 0] = rflu(a0.x); qp0[4 * gg + 1] = rflu(a0.y);         \
      qp0[4 * gg + 2] = rflu(a0.z); qp0[4 * gg + 3] = rflu(a0.w);         \
      qp1[4 * gg + 0] = rflu(a1.x); qp1[4 * gg + 1] = rflu(a1.y);         \
      qp1[4 * gg + 2] = rflu(a1.z); qp1[4 * gg + 3] = rflu(a1.w);         \
    }                                                                     \
  }

// ---------------------------------------------------------------------------
// Kernel 0: pack W fp32 [256][768] into f16 pair-quads Wq[k/8][768] (uint4:
// components pack k-pairs (0,1)(2,3)(4,5)(6,7)). grid = (96, 2), block = 256
// ---------------------------------------------------------------------------
__global__ __launch_bounds__(256) void wpack_kernel(
    const float* __restrict__ W_cls, const float* __restrict__ W_reg,
    unsigned* __restrict__ Wp_cls, unsigned* __restrict__ Wp_reg) {
  const int idx = blockIdx.x * 256 + threadIdx.x;  // uint4 index, 0..24575
  const int kq = idx / 768, c = idx % 768;
  const float* __restrict__ W = blockIdx.y ? W_reg : W_cls;
  uint4* __restrict__ Wq = (uint4*)(blockIdx.y ? Wp_reg : Wp_cls);
  uint4 o;
  o.x = h2u((half2_t){(_Float16)W[(8 * kq + 0) * 768 + c],
                      (_Float16)W[(8 * kq + 1) * 768 + c]});
  o.y = h2u((half2_t){(_Float16)W[(8 * kq + 2) * 768 + c],
                      (_Float16)W[(8 * kq + 3) * 768 + c]});
  o.z = h2u((half2_t){(_Float16)W[(8 * kq + 4) * 768 + c],
                      (_Float16)W[(8 * kq + 5) * 768 + c]});
  o.w = h2u((half2_t){(_Float16)W[(8 * kq + 6) * 768 + c],
                      (_Float16)W[(8 * kq + 7) * 768 + c]});
  Wq[idx] = o;
}

// ---------------------------------------------------------------------------
// Kernel 1: QKV projection via f16 W + fdot2, 8 rows/block (W traffic halved
// vs r16's 4-row — qkv is W-traffic-bound now that fdot2 halved its VALU).
// grid = (250, 2), block = 256
// ---------------------------------------------------------------------------
__global__ __launch_bounds__(256) void qkv_norm_kernel(
    const float* __restrict__ x_cls, const float* __restrict__ x_reg,
    const unsigned* __restrict__ Wp_cls, const unsigned* __restrict__ Wp_reg,
    _Float16* __restrict__ qc_h, _Float16* __restrict__ qr_h,
    _Float16* __restrict__ kc_h, _Float16* __restrict__ kr_h,
    _Float16* __restrict__ vn_h, float* __restrict__ v_rm,
    _Float16* __restrict__ v_h) {
  __shared__ unsigned xs_p[8][128];  // packed f16 x rows
  __shared__ float res[8][768];
  __shared__ float inv_norm[192];

  const int n0 = blockIdx.x * 8;
  const int which = blockIdx.y;
  const int tid = threadIdx.x;
  const float* __restrict__ x = which ? x_reg : x_cls;
  const uint4* __restrict__ Wq =
      (const uint4*)(which ? Wp_reg : Wp_cls);

  if (tid < 128) {
#pragma unroll
    for (int r = 0; r < 8; r++) {
      const float2 xv = ((const float2*)x)[(size_t)(n0 + r) * 128 + tid];
      xs_p[r][tid] = h2u((half2_t){(_Float16)xv.x, (_Float16)xv.y});
    }
  }
  __syncthreads();

  float acc[8][3];
#pragma unroll
  for (int r = 0; r < 8; r++) acc[r][0] = acc[r][1] = acc[r][2] = 0.f;

#pragma unroll 2
  for (int kq = 0; kq < 32; kq++) {
    const uint4 w0 = Wq[kq * 768 + tid];
    const uint4 w1 = Wq[kq * 768 + tid + 256];
    const uint4 w2 = Wq[kq * 768 + tid + 512];
#pragma unroll
    for (int r = 0; r < 8; r++) {
      const uint4 xp = *(const uint4*)&xs_p[r][kq * 4];
      acc[r][0] = fdot2f(w0.x, xp.x, acc[r][0]);
      acc[r][0] = fdot2f(w0.y, xp.y, acc[r][0]);
      acc[r][0] = fdot2f(w0.z, xp.z, acc[r][0]);
      acc[r][0] = fdot2f(w0.w, xp.w, acc[r][0]);
      acc[r][1] = fdot2f(w1.x, xp.x, acc[r][1]);
      acc[r][1] = fdot2f(w1.y, xp.y, acc[r][1]);
      acc[r][1] = fdot2f(w1.z, xp.z, acc[r][1]);
      acc[r][1] = fdot2f(w1.w, xp.w, acc[r][1]);
      acc[r][2] = fdot2f(w2.x, xp.x, acc[r][2]);
      acc[r][2] = fdot2f(w2.y, xp.y, acc[r][2]);
      acc[r][2] = fdot2f(w2.z, xp.z, acc[r][2]);
      acc[r][2] = fdot2f(w2.w, xp.w, acc[r][2]);
    }
  }
#pragma unroll
  for (int r = 0; r < 8; r++) {
    res[r][tid] = acc[r][0];
    res[r][tid + 256] = acc[r][1];
    res[r][tid + 512] = acc[r][2];
  }
  __syncthreads();

  if (tid < 192) {
    const int r = tid / 24, grp = tid % 24;
    float ss = 0.f;
#pragma unroll
    for (int d = 0; d < HD; d++) {
      const float v = res[r][grp * 32 + d];
      ss += v * v;
    }
    inv_norm[tid] = 1.0f / (sqrtf(ss) + EPSF);
  }
  __syncthreads();

#pragma unroll
  for (int j = 0; j < 3; j++) {
    const int c = tid + j * 256;
    const int qkv = c >> 8, grp = c >> 5;
    const int h = grp & 7, d = c & 31;
    const int gg = d >> 3, dd = d & 7;
#pragma unroll
    for (int r = 0; r < 8; r++) {
      const int n = n0 + r;
      const float val = res[r][c];
      const float nval = val * inv_norm[r * 24 + grp];
      const size_t fi = ((size_t)(h * 4 + gg) * N_TOK + n) * 8 + dd;
      if (qkv == 0) {
        (which ? qr_h : qc_h)[fi] = (_Float16)nval;
      } else if (qkv == 1) {
        (which ? kr_h : kc_h)[fi] = (_Float16)nval;
      } else if (which == 0) {
        v_rm[(h * N_TOK + n) * HD + d] = val;
        vn_h[fi] = (_Float16)nval;
        v_h[((size_t)h * N_TOK + n) * HD + d] = (_Float16)val;
      }
    }
  }
}

// ---------------------------------------------------------------------------
// Kernel 2: r16 structure with DEFERRED normalization: C and R sweeps run
// back-to-back with no reduction between (sums carried in registers); ONE
// packed block_sum4 (2 syncs) replaces four block_sum256 (8 syncs) per head.
// Per-head syncs 11 -> 5; R's prefetch overlaps C's tail. Math identical.
// grid = 1000, block = 256
// ---------------------------------------------------------------------------
__global__ __launch_bounds__(256) void attn17_kernel(
    const _Float16* __restrict__ qc_h, const _Float16* __restrict__ qr_h,
    const _Float16* __restrict__ kc_h, const _Float16* __restrict__ kr_h,
    const _Float16* __restrict__ vn_h, const float* __restrict__ v_rm,
    const _Float16* __restrict__ v_h,
    float* __restrict__ out_x, float* __restrict__ out_sim) {
  __shared__ float s_attn[2][SPAD];  // 16 KB; tails stay 0 for PV
  __shared__ float s_union[4608];    // 18.4 KB: er[2][2000] / part (str 17)
  __shared__ float red[16];

  float* __restrict__ s_er = s_union;
  float* __restrict__ part = s_union;  // [64 slices][4 g2] units of 17 floats

  const int tid = threadIdx.x;
  const int i0 = blockIdx.x * 2;
  const int i1 = i0 + 1;
  const int bs = (i0 / 10) * 10;  // i0 even -> i0,i1 share the same decade

  float sim0[NSLOT], sim1[NSLOT], raw0[NSLOT], raw1[NSLOT];
#pragma unroll
  for (int t = 0; t < NSLOT; t++) {
    sim0[t] = 0.f; sim1[t] = 0.f; raw0[t] = 0.f; raw1[t] = 0.f;
  }
  if (tid < SPAD - N_TOK) {
    s_attn[0][N_TOK + tid] = 0.f;
    s_attn[1][N_TOK + tid] = 0.f;
  }
  __syncthreads();

  unsigned qp0[16], qp1[16];  // packed f16 query pairs, wave-uniform -> SGPR

  // pipelined sweep over the 8 m-slots of one f16 K plane: emit(t,d0,d1)
  auto sweep = [&](const uint4* __restrict__ kt4, auto&& emit) {
    uint4 ka[4], kb[4];
#pragma unroll
    for (int g_ = 0; g_ < 4; g_++) ka[g_] = kt4[g_ * N_TOK + tid];  // t=0
#pragma unroll
    for (int t = 0; t < NSLOT; t++) {
      if (t < NSLOT - 1) {  // prefetch t+1 while computing t
        const int m1 = tid + 256 * (t + 1);
        const bool v1 = (t + 1 < 7) || (tid < NTAIL);
        const int mc1 = v1 ? m1 : (N_TOK - 1);
#pragma unroll
        for (int g_ = 0; g_ < 4; g_++) kb[g_] = kt4[g_ * N_TOK + mc1];
      }
      float d0 = 0.f, d1 = 0.f;
#pragma unroll
      for (int g_ = 0; g_ < 4; g_++) {
        d0 = fdot2f(ka[g_].x, qp0[4 * g_ + 0], d0);
        d0 = fdot2f(ka[g_].y, qp0[4 * g_ + 1], d0);
        d0 = fdot2f(ka[g_].z, qp0[4 * g_ + 2], d0);
        d0 = fdot2f(ka[g_].w, qp0[4 * g_ + 3], d0);
        d1 = fdot2f(ka[g_].x, qp1[4 * g_ + 0], d1);
        d1 = fdot2f(ka[g_].y, qp1[4 * g_ + 1], d1);
        d1 = fdot2f(ka[g_].z, qp1[4 * g_ + 2], d1);
        d1 = fdot2f(ka[g_].w, qp1[4 * g_ + 3], d1);
      }
      emit(t, d0, d1);
#pragma unroll
      for (int g_ = 0; g_ < 4; g_++) ka[g_] = kb[g_];
    }
  };

  for (int hh = 0; hh < NH; hh++) {
    const int h = (blockIdx.x + hh) & 7;  // XCD-local head schedule

    float sums[4] = {0.f, 0.f, 0.f, 0.f};  // ls0, ls1, lr0, lr1

    // ===== phase C: cls scores -> e = exp(s-25) -> s_attn (unnormalized) ===
    LOAD_QPAIR(qc_h);
    sweep((const uint4*)kc_h + (size_t)h * 4 * N_TOK,
          [&](int t, float d0, float d1) {
            const int m = tid + 256 * t;
            const bool valid = (t < 7) || (tid < NTAIL);
            const float e0 = valid ? __expf(d0 * SCALE - SCALE) : 0.f;
            const float e1 = valid ? __expf(d1 * SCALE - SCALE) : 0.f;
            sums[0] += e0; sums[1] += e1;
            if (valid) {
              s_attn[0][m] = e0;
              s_attn[1][m] = e1;
            }
          });

    // ===== phase R: reg scores -> s_er — NO reduction between phases =====
    LOAD_QPAIR(qr_h);
    sweep((const uint4*)kr_h + (size_t)h * 4 * N_TOK,
          [&](int t, float d0, float d1) {
            const int m = tid + 256 * t;
            const bool valid = (t < 7) || (tid < NTAIL);
            const float e0 = valid ? __expf(d0 * SCALE - SCALE) : 0.f;
            const float e1 = valid ? __expf(d1 * SCALE - SCALE) : 0.f;
            sums[2] += e0; sums[3] += e1;
            if (valid) {
              s_er[m] = e0;
              s_er[N_TOK + m] = e1;
            }
          });

    // ===== ONE packed reduction for all 4 softmax sums =====
    block_sum4(sums, red);
    const float n0c = 0.5f / sums[0], n1c = 0.5f / sums[1];
    const float n0r = 0.5f / sums[2], n1r = 0.5f / sums[3];

    // ===== combine, mask, sim += =====
#pragma unroll
    for (int t = 0; t < NSLOT; t++) {
      const int m = tid + 256 * t;
      if ((t < 7) || (tid < NTAIL)) {
        float a0 = s_attn[0][m] * n0c + s_er[m] * n0r;
        float a1 = s_attn[1][m] * n1c + s_er[N_TOK + m] * n1r;
        if (m >= bs && m < bs + 9) {
          if (m != i0) a0 = 0.f;
          if (m != i1) a1 = 0.f;
        }
        s_attn[0][m] = a0;
        s_attn[1][m] = a1;
        sim0[t] += a0;
        sim1[t] += a1;
      }
    }

    // ===== phase V: vn cosine -> raw += =====
    LOAD_QPAIR(vn_h);
    sweep((const uint4*)vn_h + (size_t)h * 4 * N_TOK,
          [&](int t, float d0, float d1) {
            const bool valid = (t < 7) || (tid < NTAIL);
            if (valid) { raw0[t] += d0; raw1[t] += d1; }
          });
    __syncthreads();  // s_attn final; s_er reads done -> part may reuse

    // ===== attn @ V : f16 V row-major, one uint4 = 8 d per load =====
    {
      const int g2 = tid & 3;        // d-group of 8
      const int slice = tid >> 2;    // 64 slices x 32 m
      const int m0 = slice * 32;
      float acc0[8], acc1[8];
#pragma unroll
      for (int e = 0; e < 8; e++) { acc0[e] = 0.f; acc1[e] = 0.f; }
      const _Float16* __restrict__ vb =
          v_h + (size_t)h * N_TOK * HD + g2 * 8;
#pragma unroll 2
      for (int jj = 0; jj < 8; jj++) {
        const int m = m0 + 4 * ((jj + slice) & 7);  // rotated: <=2-way LDS
        const float4 av0 = *(const float4*)&s_attn[0][m];
        const float4 av1 = *(const float4*)&s_attn[1][m];
        // m can reach 2047; av=0 there. v_h overrun (<=1.5k elems) lands in
        // the adjacent f16 plane (finite values; x0 = 0).
        uint4 vv[4];
#pragma unroll
        for (int mm = 0; mm < 4; mm++) {
          vv[mm] = *(const uint4*)(vb + (size_t)(m + mm) * HD);
        }
#pragma unroll
        for (int mm = 0; mm < 4; mm++) {
          const float a0 = ((const float*)&av0)[mm];
          const float a1 = ((const float*)&av1)[mm];
          const unsigned* vp = (const unsigned*)&vv[mm];
#pragma unroll
          for (int e = 0; e < 4; e++) {
            const half2_t hv = u2h(vp[e]);
            const float vx = (float)hv.x, vy = (float)hv.y;
            acc0[2 * e] += a0 * vx;
            acc0[2 * e + 1] += a0 * vy;
            acc1[2 * e] += a1 * vx;
            acc1[2 * e + 1] += a1 * vy;
          }
        }
      }
      __syncthreads();  // er reads in combine long done; part write safe
      float* pu = part + (size_t)(slice * 4 + g2) * 17;  // stride 17
#pragma unroll
      for (int e = 0; e < 8; e++) {
        pu[e] = acc0[e];
        pu[8 + e] = acc1[e];
      }
    }
    __syncthreads();
    if (tid < 64) {
      const int q = tid >> 5, d = tid & 31;
      const int g = d >> 3, e = d & 7;
      float s = 0.f;
#pragma unroll 8
      for (int sl = 0; sl < 64; sl++) {
        s += part[(size_t)(sl * 4 + g) * 17 + q * 8 + e];
      }
      const int irow = q ? i1 : i0;
      out_x[(size_t)irow * 512 + h * 32 + d] = s;
    } else if (tid >= 64 && tid < 128) {
      const int q = (tid - 64) >> 5, d = (tid - 64) & 31;
      const int irow = q ? i1 : i0;
      out_x[(size_t)irow * 512 + 256 + h * 32 + d] =
          v_rm[((size_t)h * N_TOK + irow) * HD + d];
    }
    __syncthreads();  // part reads done -> s_er reuse next head
  }

  // ===== sim_round2 epilogue, from registers =====
#pragma unroll
  for (int q = 0; q < 2; q++) {
    const int irow = q ? i1 : i0;
    float* __restrict__ sim = q ? sim1 : sim0;
    float* __restrict__ raw = q ? raw1 : raw0;

    float lm = -1e30f;
#pragma unroll
    for (int t = 0; t < NSLOT; t++) {
      if ((t < 7) || (tid < NTAIL)) lm = fmaxf(lm, sim[t] * 0.125f);
    }
    const float M = block_max256(lm, red);

    float ls = 0.f;
#pragma unroll
    for (int t = 0; t < NSLOT; t++) {
      const bool valid = (t < 7) || (tid < NTAIL);
      const float e = valid ? __expf(sim[t] * 0.125f - M) : 0.f;
      sim[t] = e;
      ls += e;
    }
    const float S = block_sum256(ls, red);
    const float invS = 1.0f / S;

    float lms = 0.f;
#pragma unroll
    for (int t = 0; t < NSLOT; t++) {
      const bool valid = (t < 7) || (tid < NTAIL);
      const float p = sim[t] * invS;
      const float mp = (valid && (raw[t] * 0.125f > SIM_TH)) ? p : 0.f;
      sim[t] = mp;
      lms += mp;
    }
    const float MS = block_sum256(lms, red);
    const float invMS = 1.0f / (MS + EPSF);

#pragma unroll
    for (int t = 0; t < NSLOT; t++) {
      const int m = tid + 256 * t;
      if ((t < 7) || (tid < NTAIL)) {
        out_sim[(size_t)irow * N_TOK + m] = sim[t] * invMS;
      }
    }
  }
}

// ---------------------------------------------------------------------------
extern "C" void kernel_launch(void* const* d_in, const int* in_sizes, int n_in,
                              void* d_out, int out_size, void* d_ws,
                              size_t ws_size, hipStream_t stream) {
  const float* x_cls = (const float*)d_in[0];
  const float* x_reg = (const float*)d_in[1];
  const float* W_cls = (const float*)d_in[2];
  const float* W_reg = (const float*)d_in[3];

  // ws layout: v_rm fp32, v_h f16 (NOT last: PV overrun must hit finite f16
  // data), then the score planes, then packed W.
  const size_t seg = (size_t)NH * N_TOK * HD;  // 512000 elements
  float* v_rm = (float*)d_ws;
  _Float16* v_h = (_Float16*)(v_rm + seg);
  _Float16* qc_h = v_h + seg;
  _Float16* qr_h = qc_h + seg;
  _Float16* kc_h = qr_h + seg;
  _Float16* kr_h = kc_h + seg;
  _Float16* vn_h = kr_h + seg;
  unsigned* Wp_cls = (unsigned*)(vn_h + seg);  // 98304 uints each
  unsigned* Wp_reg = Wp_cls + 98304;

  dim3 g0(96, 2);
  wpack_kernel<<<g0, 256, 0, stream>>>(W_cls, W_reg, Wp_cls, Wp_reg);

  dim3 g1(250, 2);
  qkv_norm_kernel<<<g1, 256, 0, stream>>>(x_cls, x_reg, Wp_cls, Wp_reg, qc_h,
                                          qr_h, kc_h, kr_h, vn_h, v_rm, v_h);

  float* out_x = (float*)d_out;                  // [2000, 512]
  float* out_sim = out_x + (size_t)N_TOK * 512;  // [2000, 2000]
  attn17_kernel<<<1000, 256, 0, stream>>>(qc_h, qr_h, kc_h, kr_h, vn_h, v_rm,
                                          v_h, out_x, out_sim);
}